// Round 3
// baseline (5981.808 us; speedup 1.0000x reference)
//
#include <hip/hip_runtime.h>
#include <math.h>

// Problem constants
#define B_   32
#define L_   128
#define W_   16
#define CE_  64     // char embed
#define NF_  128    // num filters
#define WE_  256    // word embed
#define E_   384    // NF_ + WE_
#define H_   512
#define G4_  2048   // 4*H
#define O1_  512
#define NC_  17
#define NBLK 256    // persistent LSTM grid (1 block/CU)

// ---------------------------------------------------------------------------
// Kernel 0: transpose conv weights [F][C][K] -> [C][K][F] for coalesced reads
// ---------------------------------------------------------------------------
__global__ __launch_bounds__(256) void conv_transpose_k(
    const float* __restrict__ cw, float* __restrict__ cwT)
{
    int i = blockIdx.x * 256 + threadIdx.x;   // 128*64*3 = 24576 exact
    int f = i / 192;
    int rem = i - f * 192;
    int c = rem / 3;
    int k = rem - c * 3;
    cwT[(c * 3 + k) * NF_ + f] = cw[i];
}

// ---------------------------------------------------------------------------
// Kernel 1: char embed gather + conv1d(k=3,pad=1) + relu + maxpool + word
// embed concat -> x [B*L, 384].  One block per (b,l), 64 threads,
// 2 filters/thread.
// ---------------------------------------------------------------------------
__global__ __launch_bounds__(64) void embed_cnn(
    const int* __restrict__ word_ids, const int* __restrict__ char_ids,
    const float* __restrict__ char_emb, const float* __restrict__ word_emb,
    const float* __restrict__ cwT, const float* __restrict__ conv_b,
    float* __restrict__ x)
{
    __shared__ float ce[CE_][20];   // [c][w+1]; slots 0..17 used (0,17 = pad)
    __shared__ int ids[W_];
    int bl = blockIdx.x;            // 0..4095, bl = b*L + l
    int tid = threadIdx.x;          // 0..63

    if (tid < W_) ids[tid] = char_ids[bl * W_ + tid];
    ce[tid][0] = 0.f;
    ce[tid][17] = 0.f;
    __syncthreads();

    for (int i = tid; i < W_ * CE_; i += 64) {
        int w = i >> 6, c = i & 63;
        ce[c][w + 1] = char_emb[ids[w] * CE_ + c];
    }
    __syncthreads();

    int f0 = tid, f1 = tid + 64;
    float acc0[W_], acc1[W_];
#pragma unroll
    for (int w = 0; w < W_; w++) { acc0[w] = 0.f; acc1[w] = 0.f; }

    for (int c = 0; c < CE_; c++) {
        float win[18];
        float4 v0 = *(const float4*)&ce[c][0];
        float4 v1 = *(const float4*)&ce[c][4];
        float4 v2 = *(const float4*)&ce[c][8];
        float4 v3 = *(const float4*)&ce[c][12];
        win[0]=v0.x; win[1]=v0.y; win[2]=v0.z; win[3]=v0.w;
        win[4]=v1.x; win[5]=v1.y; win[6]=v1.z; win[7]=v1.w;
        win[8]=v2.x; win[9]=v2.y; win[10]=v2.z; win[11]=v2.w;
        win[12]=v3.x; win[13]=v3.y; win[14]=v3.z; win[15]=v3.w;
        win[16] = ce[c][16];
        win[17] = ce[c][17];
        const float* wp = cwT + c * 3 * NF_;
        float k00 = wp[f0], k01 = wp[NF_ + f0], k02 = wp[2 * NF_ + f0];
        float k10 = wp[f1], k11 = wp[NF_ + f1], k12 = wp[2 * NF_ + f1];
#pragma unroll
        for (int w = 0; w < W_; w++) {
            acc0[w] += win[w] * k00 + win[w + 1] * k01 + win[w + 2] * k02;
            acc1[w] += win[w] * k10 + win[w + 1] * k11 + win[w + 2] * k12;
        }
    }
    float m0 = acc0[0], m1 = acc1[0];
#pragma unroll
    for (int w = 1; w < W_; w++) { m0 = fmaxf(m0, acc0[w]); m1 = fmaxf(m1, acc1[w]); }
    m0 = fmaxf(0.f, m0 + conv_b[f0]);
    m1 = fmaxf(0.f, m1 + conv_b[f1]);
    x[bl * E_ + f0] = m0;
    x[bl * E_ + f1] = m1;

    // word embedding: 256 floats, 1 float4 per thread
    int wid = word_ids[bl];
    float4 wv = *(const float4*)&word_emb[wid * WE_ + tid * 4];
    *(float4*)&x[bl * E_ + NF_ + tid * 4] = wv;
}

// ---------------------------------------------------------------------------
// Kernel 2: generic tiled fp32 GEMM  C = A[M,K] @ W[N,K]^T + bias, with
// optional ELU and output-row remap (mode 0: none, 1: fwd time-major,
// 2: bwd reversed time-major).  64x64 tile, BK=16, 4x4 per thread.
// ---------------------------------------------------------------------------
__global__ __launch_bounds__(256) void gemm_bias_act(
    const float* __restrict__ A, const float* __restrict__ Wt,
    const float* __restrict__ bias, float* __restrict__ C,
    int M, int N, int K, int mode, int act)
{
    __shared__ float As[16][68];
    __shared__ float Bs[16][68];
    int tid = threadIdx.x;
    int bm = blockIdx.x * 64;
    int bn = blockIdx.y * 64;
    int tx = tid & 15, ty = tid >> 4;
    int r = tid >> 2, kq = (tid & 3) << 2;
    float acc[4][4] = {};

    for (int kt = 0; kt < K; kt += 16) {
        float4 av = *(const float4*)&A[(bm + r) * K + kt + kq];
        As[kq + 0][r] = av.x; As[kq + 1][r] = av.y;
        As[kq + 2][r] = av.z; As[kq + 3][r] = av.w;
        int n = bn + r;
        float4 wv = make_float4(0.f, 0.f, 0.f, 0.f);
        if (n < N) wv = *(const float4*)&Wt[n * K + kt + kq];
        Bs[kq + 0][r] = wv.x; Bs[kq + 1][r] = wv.y;
        Bs[kq + 2][r] = wv.z; Bs[kq + 3][r] = wv.w;
        __syncthreads();
#pragma unroll
        for (int k = 0; k < 16; k++) {
            float4 a = *(const float4*)&As[k][ty << 2];
            float4 b = *(const float4*)&Bs[k][tx << 2];
            acc[0][0] += a.x * b.x; acc[0][1] += a.x * b.y;
            acc[0][2] += a.x * b.z; acc[0][3] += a.x * b.w;
            acc[1][0] += a.y * b.x; acc[1][1] += a.y * b.y;
            acc[1][2] += a.y * b.z; acc[1][3] += a.y * b.w;
            acc[2][0] += a.z * b.x; acc[2][1] += a.z * b.y;
            acc[2][2] += a.z * b.z; acc[2][3] += a.z * b.w;
            acc[3][0] += a.w * b.x; acc[3][1] += a.w * b.y;
            acc[3][2] += a.w * b.z; acc[3][3] += a.w * b.w;
        }
        __syncthreads();
    }

#pragma unroll
    for (int ii = 0; ii < 4; ii++) {
        int m = bm + (ty << 2) + ii;
        int orow;
        if (mode == 0) orow = m;
        else {
            int bb = m >> 7, l = m & 127;
            int ll = (mode == 1) ? l : (127 - l);
            orow = ll * B_ + bb;
        }
#pragma unroll
        for (int jj = 0; jj < 4; jj++) {
            int n = bn + (tx << 2) + jj;
            if (n < N) {
                float v = acc[ii][jj] + bias[n];
                if (act) v = v > 0.f ? v : expm1f(v);
                C[orow * N + n] = v;
            }
        }
    }
}

// ---------------------------------------------------------------------------
// Kernel 3: persistent cooperative BLSTM — all 128 time steps in one launch.
// 256 blocks (1/CU): dir = bx>>7, 4 hidden units per block (16 gate rows),
// all 32 batch. W_hh slice (16 rows x 512 = 32KB) staged in LDS ONCE.
// c lives in registers. h double-buffered in global as [2][B][H]
// ([dir][b][k], per-lane sequential float4 streams). One device-scope
// atomic barrier per step (monotonic counter, no reset).
// ---------------------------------------------------------------------------
__global__ __launch_bounds__(256) void lstm_persistent(
    const float* __restrict__ gxf, const float* __restrict__ gxb,
    const float* __restrict__ whh_f, const float* __restrict__ whh_b,
    float* __restrict__ hA, float* __restrict__ hB,
    float* __restrict__ hcat, unsigned int* __restrict__ bar)
{
    __shared__ float wlds[16][512];   // 32 KB weight slice
    __shared__ float gl[16][32];      // gate exchange

    int bx = blockIdx.x;
    int dir = bx >> 7;
    int U0 = (bx & 127) * 4;
    int tid = threadIdx.x;
    int b = tid & 31, rr = tid >> 5;  // rr 0..7

    const float* gx  = dir ? gxb : gxf;
    const float* whh = dir ? whh_b : whh_f;

    // stage this block's 16 weight rows into LDS (once)
    for (int i = tid; i < 16 * 128; i += 256) {     // 16 rows x 128 float4
        int lr = i >> 7, kq = (i & 127) << 2;
        int R = (lr >> 2) * H_ + U0 + (lr & 3);
        *(float4*)&wlds[lr][kq] = *(const float4*)&whh[R * H_ + kq];
    }
    __syncthreads();

    int r0 = rr, r1 = rr + 8;
    int R0 = (r0 >> 2) * H_ + U0 + (r0 & 3);
    int R1 = (r1 >> 2) * H_ + U0 + (r1 & 3);
    int u = tid >> 5;                 // for update phase (tid<128): u 0..3
    float c_reg = 0.f;

    for (int t = 0; t < L_; t++) {
        const float* hp = ((t & 1) ? hB : hA) + dir * (B_ * H_);
        float*       hn = ((t & 1) ? hA : hB) + dir * (B_ * H_);

        float acc0 = gx[(t * B_ + b) * G4_ + R0];
        float acc1 = gx[(t * B_ + b) * G4_ + R1];
        const float* hrow = hp + b * H_;
#pragma unroll 16
        for (int k = 0; k < H_; k += 4) {
            float4 hv = *(const float4*)&hrow[k];
            float4 w0 = *(const float4*)&wlds[r0][k];
            float4 w1 = *(const float4*)&wlds[r1][k];
            acc0 += w0.x * hv.x + w0.y * hv.y + w0.z * hv.z + w0.w * hv.w;
            acc1 += w1.x * hv.x + w1.y * hv.y + w1.z * hv.z + w1.w * hv.w;
        }
        gl[r0][b] = acc0;
        gl[r1][b] = acc1;
        __syncthreads();

        if (tid < 128) {
            float gi = gl[u][b];
            float gf = gl[4 + u][b];
            float gg = gl[8 + u][b];
            float go = gl[12 + u][b];
            float i_ = 1.f / (1.f + expf(-gi));
            float f_ = 1.f / (1.f + expf(-gf));
            float o_ = 1.f / (1.f + expf(-go));
            float g_ = tanhf(gg);
            c_reg = f_ * c_reg + i_ * g_;
            float h_new = o_ * tanhf(c_reg);
            int j = U0 + u;
            hn[b * H_ + j] = h_new;
            int l = dir ? (L_ - 1 - t) : t;
            hcat[(b * L_ + l) * (2 * H_) + dir * H_ + j] = h_new;
        }

        if (t < L_ - 1) {
            // grid barrier: release own writes, arrive, spin, acquire
            __syncthreads();
            if (tid == 0) {
                __threadfence();
                __hip_atomic_fetch_add(bar, 1u, __ATOMIC_RELEASE,
                                       __HIP_MEMORY_SCOPE_AGENT);
                unsigned target = (unsigned)(t + 1) * NBLK;
                while (__hip_atomic_load(bar, __ATOMIC_ACQUIRE,
                                         __HIP_MEMORY_SCOPE_AGENT) < target)
                    __builtin_amdgcn_s_sleep(1);
                __threadfence();
            }
            __syncthreads();
        }
    }
}

// ---------------------------------------------------------------------------
// Launch
// ---------------------------------------------------------------------------
extern "C" void kernel_launch(void* const* d_in, const int* in_sizes, int n_in,
                              void* d_out, int out_size, void* d_ws, size_t ws_size,
                              hipStream_t stream)
{
    const int*   word_ids = (const int*)d_in[0];
    const int*   char_ids = (const int*)d_in[1];
    // d_in[2] = mask (unused by reference)
    const float* char_emb = (const float*)d_in[3];
    const float* word_emb = (const float*)d_in[4];
    const float* conv_w   = (const float*)d_in[5];
    const float* conv_b   = (const float*)d_in[6];
    const float* w_ih_f   = (const float*)d_in[7];
    const float* w_hh_f   = (const float*)d_in[8];
    const float* b_f      = (const float*)d_in[9];
    const float* w_ih_b   = (const float*)d_in[10];
    const float* w_hh_b   = (const float*)d_in[11];
    const float* b_b      = (const float*)d_in[12];
    const float* w1       = (const float*)d_in[13];
    const float* b1       = (const float*)d_in[14];
    const float* w2       = (const float*)d_in[15];
    const float* b2       = (const float*)d_in[16];
    float* out = (float*)d_out;
    float* ws  = (float*)d_ws;

    // workspace layout (floats)
    float* x    = ws + 0;          // [4096][384]
    float* gxf  = ws + 1572864;    // [128][32][2048]
    float* gxb  = ws + 9961472;    // [128][32][2048]
    float* hA   = ws + 18350080;   // [2][32][512]
    float* hB   = ws + 18382848;   // [2][32][512]
    float* hcat = ws + 18448384;   // [4096][1024]
    float* z    = ws + 22642688;   // [4096][512]
    float* cwT  = ws + 24739840;   // [64][3][128]
    unsigned int* bar = (unsigned int*)(ws + 24764416);  // barrier counter

    hipMemsetAsync(hA, 0, 2 * B_ * H_ * sizeof(float), stream);
    hipMemsetAsync(bar, 0, 256, stream);

    conv_transpose_k<<<96, 256, 0, stream>>>(conv_w, cwT);
    embed_cnn<<<4096, 64, 0, stream>>>(word_ids, char_ids, char_emb, word_emb,
                                       cwT, conv_b, x);

    dim3 g1(64, 32);
    gemm_bias_act<<<g1, 256, 0, stream>>>(x, w_ih_f, b_f, gxf, 4096, G4_, E_, 1, 0);
    gemm_bias_act<<<g1, 256, 0, stream>>>(x, w_ih_b, b_b, gxb, 4096, G4_, E_, 2, 0);

    {
        const float* a0 = gxf; const float* a1 = gxb;
        const float* a2 = w_hh_f; const float* a3 = w_hh_b;
        float* a4 = hA; float* a5 = hB; float* a6 = hcat;
        unsigned int* a7 = bar;
        void* args[] = { &a0, &a1, &a2, &a3, &a4, &a5, &a6, &a7 };
        hipLaunchCooperativeKernel((void*)lstm_persistent, dim3(NBLK), dim3(256),
                                   args, 0, stream);
    }

    dim3 g2(64, 8);
    gemm_bias_act<<<g2, 256, 0, stream>>>(hcat, w1, b1, z, 4096, O1_, 2 * H_, 0, 1);
    dim3 g3(64, 1);
    gemm_bias_act<<<g3, 256, 0, stream>>>(z, w2, b2, out, 4096, NC_, O1_, 0, 0);
}

// Round 4
// 2285.453 us; speedup vs baseline: 2.6173x; 2.6173x over previous
//
#include <hip/hip_runtime.h>
#include <math.h>

// Problem constants
#define B_   32
#define L_   128
#define W_   16
#define CE_  64     // char embed
#define NF_  128    // num filters
#define WE_  256    // word embed
#define E_   384    // NF_ + WE_
#define H_   512
#define G4_  2048   // 4*H
#define O1_  512
#define NC_  17
#define LSTM_BLOCKS 64          // 32 per direction
#define HS   (32 * 512)         // elements per h plane (bf16)

typedef __attribute__((ext_vector_type(8))) short short8_t;
typedef __attribute__((ext_vector_type(4))) float f32x4;

__device__ inline unsigned short f2bf(float x) {
    unsigned u = __float_as_uint(x);
    u += 0x7FFF + ((u >> 16) & 1);           // round-to-nearest-even
    return (unsigned short)(u >> 16);
}

// ---------------------------------------------------------------------------
// Kernel 0: transpose conv weights [F][C][K] -> [C][K][F]
// ---------------------------------------------------------------------------
__global__ __launch_bounds__(256) void conv_transpose_k(
    const float* __restrict__ cw, float* __restrict__ cwT)
{
    int i = blockIdx.x * 256 + threadIdx.x;   // 24576 exact
    int f = i / 192;
    int rem = i - f * 192;
    int c = rem / 3;
    int k = rem - c * 3;
    cwT[(c * 3 + k) * NF_ + f] = cw[i];
}

// ---------------------------------------------------------------------------
// Kernel 0b: convert both W_hh to bf16 (row-major [2048][512] per dir)
// ---------------------------------------------------------------------------
__global__ __launch_bounds__(256) void whh_to_bf16(
    const float* __restrict__ wf, const float* __restrict__ wb,
    unsigned short* __restrict__ outp)
{
    int i = blockIdx.x * 256 + threadIdx.x;   // 524288 float4 groups total
    const float* src = (i < 262144) ? wf : wb;
    int j = (i < 262144) ? i : i - 262144;
    float4 v = *(const float4*)&src[j * 4];
    unsigned short* o = outp + (size_t)i * 4;
    o[0] = f2bf(v.x); o[1] = f2bf(v.y); o[2] = f2bf(v.z); o[3] = f2bf(v.w);
}

// ---------------------------------------------------------------------------
// Kernel 1: char embed gather + conv1d(k=3,pad=1) + relu + maxpool + word
// embed concat -> x [B*L, 384]
// ---------------------------------------------------------------------------
__global__ __launch_bounds__(64) void embed_cnn(
    const int* __restrict__ word_ids, const int* __restrict__ char_ids,
    const float* __restrict__ char_emb, const float* __restrict__ word_emb,
    const float* __restrict__ cwT, const float* __restrict__ conv_b,
    float* __restrict__ x)
{
    __shared__ float ce[CE_][20];
    __shared__ int ids[W_];
    int bl = blockIdx.x;
    int tid = threadIdx.x;

    if (tid < W_) ids[tid] = char_ids[bl * W_ + tid];
    ce[tid][0] = 0.f;
    ce[tid][17] = 0.f;
    __syncthreads();

    for (int i = tid; i < W_ * CE_; i += 64) {
        int w = i >> 6, c = i & 63;
        ce[c][w + 1] = char_emb[ids[w] * CE_ + c];
    }
    __syncthreads();

    int f0 = tid, f1 = tid + 64;
    float acc0[W_], acc1[W_];
#pragma unroll
    for (int w = 0; w < W_; w++) { acc0[w] = 0.f; acc1[w] = 0.f; }

    for (int c = 0; c < CE_; c++) {
        float win[18];
        float4 v0 = *(const float4*)&ce[c][0];
        float4 v1 = *(const float4*)&ce[c][4];
        float4 v2 = *(const float4*)&ce[c][8];
        float4 v3 = *(const float4*)&ce[c][12];
        win[0]=v0.x; win[1]=v0.y; win[2]=v0.z; win[3]=v0.w;
        win[4]=v1.x; win[5]=v1.y; win[6]=v1.z; win[7]=v1.w;
        win[8]=v2.x; win[9]=v2.y; win[10]=v2.z; win[11]=v2.w;
        win[12]=v3.x; win[13]=v3.y; win[14]=v3.z; win[15]=v3.w;
        win[16] = ce[c][16];
        win[17] = ce[c][17];
        const float* wp = cwT + c * 3 * NF_;
        float k00 = wp[f0], k01 = wp[NF_ + f0], k02 = wp[2 * NF_ + f0];
        float k10 = wp[f1], k11 = wp[NF_ + f1], k12 = wp[2 * NF_ + f1];
#pragma unroll
        for (int w = 0; w < W_; w++) {
            acc0[w] += win[w] * k00 + win[w + 1] * k01 + win[w + 2] * k02;
            acc1[w] += win[w] * k10 + win[w + 1] * k11 + win[w + 2] * k12;
        }
    }
    float m0 = acc0[0], m1 = acc1[0];
#pragma unroll
    for (int w = 1; w < W_; w++) { m0 = fmaxf(m0, acc0[w]); m1 = fmaxf(m1, acc1[w]); }
    m0 = fmaxf(0.f, m0 + conv_b[f0]);
    m1 = fmaxf(0.f, m1 + conv_b[f1]);
    x[bl * E_ + f0] = m0;
    x[bl * E_ + f1] = m1;

    int wid = word_ids[bl];
    float4 wv = *(const float4*)&word_emb[wid * WE_ + tid * 4];
    *(float4*)&x[bl * E_ + NF_ + tid * 4] = wv;
}

// ---------------------------------------------------------------------------
// Kernel 2: generic tiled fp32 GEMM  C = A[M,K] @ W[N,K]^T + bias
// mode 0: C[m][n];  mode 1/2: C[(l or 127-l)*B + b][n]  (time-major gx)
// ---------------------------------------------------------------------------
__global__ __launch_bounds__(256) void gemm_bias_act(
    const float* __restrict__ A, const float* __restrict__ Wt,
    const float* __restrict__ bias, float* __restrict__ C,
    int M, int N, int K, int mode, int act)
{
    __shared__ float As[16][68];
    __shared__ float Bs[16][68];
    int tid = threadIdx.x;
    int bm = blockIdx.x * 64;
    int bn = blockIdx.y * 64;
    int tx = tid & 15, ty = tid >> 4;
    int r = tid >> 2, kq = (tid & 3) << 2;
    float acc[4][4] = {};

    for (int kt = 0; kt < K; kt += 16) {
        float4 av = *(const float4*)&A[(bm + r) * K + kt + kq];
        As[kq + 0][r] = av.x; As[kq + 1][r] = av.y;
        As[kq + 2][r] = av.z; As[kq + 3][r] = av.w;
        int n = bn + r;
        float4 wv = make_float4(0.f, 0.f, 0.f, 0.f);
        if (n < N) wv = *(const float4*)&Wt[n * K + kt + kq];
        Bs[kq + 0][r] = wv.x; Bs[kq + 1][r] = wv.y;
        Bs[kq + 2][r] = wv.z; Bs[kq + 3][r] = wv.w;
        __syncthreads();
#pragma unroll
        for (int k = 0; k < 16; k++) {
            float4 a = *(const float4*)&As[k][ty << 2];
            float4 b = *(const float4*)&Bs[k][tx << 2];
            acc[0][0] += a.x * b.x; acc[0][1] += a.x * b.y;
            acc[0][2] += a.x * b.z; acc[0][3] += a.x * b.w;
            acc[1][0] += a.y * b.x; acc[1][1] += a.y * b.y;
            acc[1][2] += a.y * b.z; acc[1][3] += a.y * b.w;
            acc[2][0] += a.z * b.x; acc[2][1] += a.z * b.y;
            acc[2][2] += a.z * b.z; acc[2][3] += a.z * b.w;
            acc[3][0] += a.w * b.x; acc[3][1] += a.w * b.y;
            acc[3][2] += a.w * b.z; acc[3][3] += a.w * b.w;
        }
        __syncthreads();
    }

#pragma unroll
    for (int ii = 0; ii < 4; ii++) {
        int m = bm + (ty << 2) + ii;
        int orow;
        if (mode == 0) orow = m;
        else {
            int bb = m >> 7, l = m & 127;
            int ll = (mode == 1) ? l : (127 - l);
            orow = ll * B_ + bb;
        }
#pragma unroll
        for (int jj = 0; jj < 4; jj++) {
            int n = bn + (tx << 2) + jj;
            if (n < N) {
                float v = acc[ii][jj] + bias[n];
                if (act) v = v > 0.f ? v : expm1f(v);
                C[orow * N + n] = v;
            }
        }
    }
}

// ---------------------------------------------------------------------------
// Kernel 3: persistent MFMA BLSTM. 64 blocks (32/dir), 256 threads = 4 waves,
// one gate per wave, 16 hidden units per block.
//   A-frags (W_hh bf16, 16 units x 512 K) live in registers the whole kernel.
//   h: bf16 hi+lo planes, [b][k] row-major, double-buffered in global.
//   gates = MFMA(W, h_hi) + MFMA(W, h_lo); gx added in update phase.
//   Cell state c in registers. Grid barrier: monotonic atomic counter.
// ---------------------------------------------------------------------------
__global__ __launch_bounds__(256) void lstm_mfma(
    const float* __restrict__ gxf, const float* __restrict__ gxb,
    const unsigned short* __restrict__ whh_bf,   // [2][2048][512] bf16
    unsigned short* __restrict__ hbuf,           // [2 buf][2 dir][2 pl][32][512]
    float* __restrict__ hcat, unsigned int* __restrict__ bar)
{
    int bx = blockIdx.x;
    int dir = bx >> 5;
    int U0 = (bx & 31) * 16;      // 16 units per block
    int tid = threadIdx.x;
    int g = tid >> 6;             // gate 0..3 (i,f,g,o) = wave id
    int l = tid & 63;
    int lr = l & 15, lk = l >> 4; // frag row (unit/batch) and k-chunk

    const float* gx = dir ? gxb : gxf;

    // A-fragments: rows = units U0+lr of gate g, all K=512 (16 ksteps)
    short8_t afrag[16];
    {
        const unsigned short* wrow =
            whh_bf + (size_t)dir * (2048 * 512)
                   + ((size_t)(g * 512 + U0 + lr)) * 512 + lk * 8;
#pragma unroll
        for (int ks = 0; ks < 16; ks++)
            afrag[ks] = *(const short8_t*)(wrow + ks * 32);
    }

    // update-phase mapping: thread handles (b=ub, u=uu) and (b=ub+16, u=uu)
    int uu = tid & 15, ub = tid >> 4;
    float c0 = 0.f, c1 = 0.f;

    __shared__ float gl[4 * 32 * 17];   // [gate][b][u] padded

    for (int t = 0; t < L_; t++) {
        int rb = t & 1;
        const unsigned short* hrd = hbuf + rb * (4 * HS) + dir * (2 * HS);
        unsigned short*       hwr = hbuf + (rb ^ 1) * (4 * HS) + dir * (2 * HS);

        // prefetch gx for the update phase (independent of h)
        float gxv0[4], gxv1[4];
        {
            const float* gxt = gx + (size_t)t * B_ * G4_;
#pragma unroll
            for (int gg = 0; gg < 4; gg++) {
                gxv0[gg] = gxt[ub * G4_ + gg * H_ + U0 + uu];
                gxv1[gg] = gxt[(ub + 16) * G4_ + gg * H_ + U0 + uu];
            }
        }

        // MFMA phase: D[16 units][32 b] for gate g
        f32x4 d0 = {0.f, 0.f, 0.f, 0.f};
        f32x4 d1 = {0.f, 0.f, 0.f, 0.f};
        {
            const unsigned short* b0h = hrd + lr * 512 + lk * 8;        // nt0 hi
            const unsigned short* b1h = hrd + (16 + lr) * 512 + lk * 8; // nt1 hi
            const unsigned short* b0l = b0h + HS;                        // lo
            const unsigned short* b1l = b1h + HS;
#pragma unroll
            for (int ks = 0; ks < 16; ks++) {
                short8_t bh0 = *(const short8_t*)(b0h + ks * 32);
                short8_t bl0 = *(const short8_t*)(b0l + ks * 32);
                short8_t bh1 = *(const short8_t*)(b1h + ks * 32);
                short8_t bl1 = *(const short8_t*)(b1l + ks * 32);
                d0 = __builtin_amdgcn_mfma_f32_16x16x32_bf16(afrag[ks], bh0, d0, 0, 0, 0);
                d0 = __builtin_amdgcn_mfma_f32_16x16x32_bf16(afrag[ks], bl0, d0, 0, 0, 0);
                d1 = __builtin_amdgcn_mfma_f32_16x16x32_bf16(afrag[ks], bh1, d1, 0, 0, 0);
                d1 = __builtin_amdgcn_mfma_f32_16x16x32_bf16(afrag[ks], bl1, d1, 0, 0, 0);
            }
        }
        // D layout: col(b) = lr, row(u) = lk*4 + r
#pragma unroll
        for (int r = 0; r < 4; r++) {
            gl[(g * 32 + lr) * 17 + lk * 4 + r]      = d0[r];
            gl[(g * 32 + 16 + lr) * 17 + lk * 4 + r] = d1[r];
        }
        __syncthreads();

        // cell update: pairs (ub, uu) and (ub+16, uu)
        {
            float ga0[4], ga1[4];
#pragma unroll
            for (int gg = 0; gg < 4; gg++) {
                ga0[gg] = gl[(gg * 32 + ub) * 17 + uu] + gxv0[gg];
                ga1[gg] = gl[(gg * 32 + ub + 16) * 17 + uu] + gxv1[gg];
            }
            float i0 = 1.f / (1.f + expf(-ga0[0]));
            float f0_ = 1.f / (1.f + expf(-ga0[1]));
            float g0 = tanhf(ga0[2]);
            float o0 = 1.f / (1.f + expf(-ga0[3]));
            c0 = f0_ * c0 + i0 * g0;
            float h0 = o0 * tanhf(c0);

            float i1 = 1.f / (1.f + expf(-ga1[0]));
            float f1_ = 1.f / (1.f + expf(-ga1[1]));
            float g1 = tanhf(ga1[2]);
            float o1 = 1.f / (1.f + expf(-ga1[3]));
            c1 = f1_ * c1 + i1 * g1;
            float h1 = o1 * tanhf(c1);

            int j = U0 + uu;
            unsigned short h0hi = f2bf(h0);
            unsigned short h1hi = f2bf(h1);
            float h0r = h0 - __uint_as_float((unsigned)h0hi << 16);
            float h1r = h1 - __uint_as_float((unsigned)h1hi << 16);
            hwr[ub * 512 + j]            = h0hi;
            hwr[HS + ub * 512 + j]       = f2bf(h0r);
            hwr[(ub + 16) * 512 + j]     = h1hi;
            hwr[HS + (ub + 16) * 512 + j] = f2bf(h1r);

            int ll = dir ? (L_ - 1 - t) : t;
            hcat[((size_t)ub * L_ + ll) * (2 * H_) + dir * H_ + j]        = h0;
            hcat[((size_t)(ub + 16) * L_ + ll) * (2 * H_) + dir * H_ + j] = h1;
        }

        if (t < L_ - 1) {
            __syncthreads();
            if (tid == 0) {
                __threadfence();
                __hip_atomic_fetch_add(bar, 1u, __ATOMIC_RELEASE,
                                       __HIP_MEMORY_SCOPE_AGENT);
                unsigned target = (unsigned)(t + 1) * LSTM_BLOCKS;
                while (__hip_atomic_load(bar, __ATOMIC_ACQUIRE,
                                         __HIP_MEMORY_SCOPE_AGENT) < target)
                    __builtin_amdgcn_s_sleep(2);
                __threadfence();
            }
            __syncthreads();
        }
    }
}

// ---------------------------------------------------------------------------
// Launch
// ---------------------------------------------------------------------------
extern "C" void kernel_launch(void* const* d_in, const int* in_sizes, int n_in,
                              void* d_out, int out_size, void* d_ws, size_t ws_size,
                              hipStream_t stream)
{
    const int*   word_ids = (const int*)d_in[0];
    const int*   char_ids = (const int*)d_in[1];
    const float* char_emb = (const float*)d_in[3];
    const float* word_emb = (const float*)d_in[4];
    const float* conv_w   = (const float*)d_in[5];
    const float* conv_b   = (const float*)d_in[6];
    const float* w_ih_f   = (const float*)d_in[7];
    const float* w_hh_f   = (const float*)d_in[8];
    const float* b_f      = (const float*)d_in[9];
    const float* w_ih_b   = (const float*)d_in[10];
    const float* w_hh_b   = (const float*)d_in[11];
    const float* b_b      = (const float*)d_in[12];
    const float* w1       = (const float*)d_in[13];
    const float* b1       = (const float*)d_in[14];
    const float* w2       = (const float*)d_in[15];
    const float* b2       = (const float*)d_in[16];
    float* out = (float*)d_out;
    float* ws  = (float*)d_ws;

    // workspace layout (float offsets)
    float* x    = ws + 0;            // [4096][384]
    float* gxf  = ws + 1572864;      // [128][32][2048]
    float* gxb  = ws + 9961472;      // [128][32][2048]
    float* hcat = ws + 18350080;     // [4096][1024]
    unsigned short* whhbf = (unsigned short*)(ws + 22544384);  // 2x2048x512 bf16
    unsigned short* hbuf  = (unsigned short*)(ws + 23592960);  // 2x2x2x16384 bf16
    float* cwT  = ws + 23658496;     // [64][3][128]
    unsigned int* bar = (unsigned int*)(ws + 23683072);
    float* z    = ws + 0;            // [4096][512] reuses x/gxf (dead by then)

    hipMemsetAsync(hbuf, 0, 4 * HS * sizeof(unsigned short), stream);  // buf0
    hipMemsetAsync(bar, 0, 256, stream);

    conv_transpose_k<<<96, 256, 0, stream>>>(conv_w, cwT);
    whh_to_bf16<<<2048, 256, 0, stream>>>(w_hh_f, w_hh_b, whhbf);
    embed_cnn<<<4096, 64, 0, stream>>>(word_ids, char_ids, char_emb, word_emb,
                                       cwT, conv_b, x);

    dim3 g1(64, 32);
    gemm_bias_act<<<g1, 256, 0, stream>>>(x, w_ih_f, b_f, gxf, 4096, G4_, E_, 1, 0);
    gemm_bias_act<<<g1, 256, 0, stream>>>(x, w_ih_b, b_b, gxb, 4096, G4_, E_, 2, 0);

    {
        const float* a0 = gxf; const float* a1 = gxb;
        const unsigned short* a2 = whhbf;
        unsigned short* a3 = hbuf;
        float* a4 = hcat;
        unsigned int* a5 = bar;
        void* args[] = { &a0, &a1, &a2, &a3, &a4, &a5 };
        hipLaunchCooperativeKernel((void*)lstm_mfma, dim3(LSTM_BLOCKS), dim3(256),
                                   args, 0, stream);
    }

    dim3 g2(64, 8);
    gemm_bias_act<<<g2, 256, 0, stream>>>(hcat, w1, b1, z, 4096, O1_, 2 * H_, 0, 1);
    dim3 g3(64, 1);
    gemm_bias_act<<<g3, 256, 0, stream>>>(z, w2, b2, out, 4096, NC_, O1_, 0, 0);
}

// Round 5
// 910.916 us; speedup vs baseline: 6.5668x; 2.5090x over previous
//
#include <hip/hip_runtime.h>
#include <math.h>

// Problem constants
#define B_   32
#define L_   128
#define W_   16
#define CE_  64     // char embed
#define NF_  128    // num filters
#define WE_  256    // word embed
#define E_   384    // NF_ + WE_
#define H_   512
#define G4_  2048   // 4*H
#define O1_  512
#define NC_  17
#define LSTM_BLOCKS 64          // 32 per direction
#define AGENT_SC __HIP_MEMORY_SCOPE_AGENT

typedef __attribute__((ext_vector_type(4))) float f32x4;
typedef _Float16 half8 __attribute__((ext_vector_type(8)));

// ---------------------------------------------------------------------------
// Kernel 0: transpose conv weights [F][C][K] -> [C][K][F]
// ---------------------------------------------------------------------------
__global__ __launch_bounds__(256) void conv_transpose_k(
    const float* __restrict__ cw, float* __restrict__ cwT)
{
    int i = blockIdx.x * 256 + threadIdx.x;   // 24576 exact
    int f = i / 192;
    int rem = i - f * 192;
    int c = rem / 3;
    int k = rem - c * 3;
    cwT[(c * 3 + k) * NF_ + f] = cw[i];
}

// ---------------------------------------------------------------------------
// Kernel 0b: convert both W_hh to fp16 (row-major [2048][512] per dir)
// ---------------------------------------------------------------------------
__global__ __launch_bounds__(256) void whh_to_f16(
    const float* __restrict__ wf, const float* __restrict__ wb,
    _Float16* __restrict__ outp)
{
    int i = blockIdx.x * 256 + threadIdx.x;   // 524288 float4 groups total
    const float* src = (i < 262144) ? wf : wb;
    int j = (i < 262144) ? i : i - 262144;
    float4 v = *(const float4*)&src[j * 4];
    _Float16* o = outp + (size_t)i * 4;
    o[0] = (_Float16)v.x; o[1] = (_Float16)v.y;
    o[2] = (_Float16)v.z; o[3] = (_Float16)v.w;
}

// ---------------------------------------------------------------------------
// Kernel 1: char embed gather + conv1d(k=3,pad=1) + relu + maxpool + word
// embed concat -> x [B*L, 384]
// ---------------------------------------------------------------------------
__global__ __launch_bounds__(64) void embed_cnn(
    const int* __restrict__ word_ids, const int* __restrict__ char_ids,
    const float* __restrict__ char_emb, const float* __restrict__ word_emb,
    const float* __restrict__ cwT, const float* __restrict__ conv_b,
    float* __restrict__ x)
{
    __shared__ float ce[CE_][20];
    __shared__ int ids[W_];
    int bl = blockIdx.x;
    int tid = threadIdx.x;

    if (tid < W_) ids[tid] = char_ids[bl * W_ + tid];
    ce[tid][0] = 0.f;
    ce[tid][17] = 0.f;
    __syncthreads();

    for (int i = tid; i < W_ * CE_; i += 64) {
        int w = i >> 6, c = i & 63;
        ce[c][w + 1] = char_emb[ids[w] * CE_ + c];
    }
    __syncthreads();

    int f0 = tid, f1 = tid + 64;
    float acc0[W_], acc1[W_];
#pragma unroll
    for (int w = 0; w < W_; w++) { acc0[w] = 0.f; acc1[w] = 0.f; }

    for (int c = 0; c < CE_; c++) {
        float win[18];
        float4 v0 = *(const float4*)&ce[c][0];
        float4 v1 = *(const float4*)&ce[c][4];
        float4 v2 = *(const float4*)&ce[c][8];
        float4 v3 = *(const float4*)&ce[c][12];
        win[0]=v0.x; win[1]=v0.y; win[2]=v0.z; win[3]=v0.w;
        win[4]=v1.x; win[5]=v1.y; win[6]=v1.z; win[7]=v1.w;
        win[8]=v2.x; win[9]=v2.y; win[10]=v2.z; win[11]=v2.w;
        win[12]=v3.x; win[13]=v3.y; win[14]=v3.z; win[15]=v3.w;
        win[16] = ce[c][16];
        win[17] = ce[c][17];
        const float* wp = cwT + c * 3 * NF_;
        float k00 = wp[f0], k01 = wp[NF_ + f0], k02 = wp[2 * NF_ + f0];
        float k10 = wp[f1], k11 = wp[NF_ + f1], k12 = wp[2 * NF_ + f1];
#pragma unroll
        for (int w = 0; w < W_; w++) {
            acc0[w] += win[w] * k00 + win[w + 1] * k01 + win[w + 2] * k02;
            acc1[w] += win[w] * k10 + win[w + 1] * k11 + win[w + 2] * k12;
        }
    }
    float m0 = acc0[0], m1 = acc1[0];
#pragma unroll
    for (int w = 1; w < W_; w++) { m0 = fmaxf(m0, acc0[w]); m1 = fmaxf(m1, acc1[w]); }
    m0 = fmaxf(0.f, m0 + conv_b[f0]);
    m1 = fmaxf(0.f, m1 + conv_b[f1]);
    x[bl * E_ + f0] = m0;
    x[bl * E_ + f1] = m1;

    int wid = word_ids[bl];
    float4 wv = *(const float4*)&word_emb[wid * WE_ + tid * 4];
    *(float4*)&x[bl * E_ + NF_ + tid * 4] = wv;
}

// ---------------------------------------------------------------------------
// Kernel 2: generic tiled fp32 GEMM  C = A[M,K] @ W[N,K]^T + bias
// mode 0: C[m][n];  mode 1/2: C[(l or 127-l)*B + b][n]  (time-major gx)
// ---------------------------------------------------------------------------
__global__ __launch_bounds__(256) void gemm_bias_act(
    const float* __restrict__ A, const float* __restrict__ Wt,
    const float* __restrict__ bias, float* __restrict__ C,
    int M, int N, int K, int mode, int act)
{
    __shared__ float As[16][68];
    __shared__ float Bs[16][68];
    int tid = threadIdx.x;
    int bm = blockIdx.x * 64;
    int bn = blockIdx.y * 64;
    int tx = tid & 15, ty = tid >> 4;
    int r = tid >> 2, kq = (tid & 3) << 2;
    float acc[4][4] = {};

    for (int kt = 0; kt < K; kt += 16) {
        float4 av = *(const float4*)&A[(bm + r) * K + kt + kq];
        As[kq + 0][r] = av.x; As[kq + 1][r] = av.y;
        As[kq + 2][r] = av.z; As[kq + 3][r] = av.w;
        int n = bn + r;
        float4 wv = make_float4(0.f, 0.f, 0.f, 0.f);
        if (n < N) wv = *(const float4*)&Wt[n * K + kt + kq];
        Bs[kq + 0][r] = wv.x; Bs[kq + 1][r] = wv.y;
        Bs[kq + 2][r] = wv.z; Bs[kq + 3][r] = wv.w;
        __syncthreads();
#pragma unroll
        for (int k = 0; k < 16; k++) {
            float4 a = *(const float4*)&As[k][ty << 2];
            float4 b = *(const float4*)&Bs[k][tx << 2];
            acc[0][0] += a.x * b.x; acc[0][1] += a.x * b.y;
            acc[0][2] += a.x * b.z; acc[0][3] += a.x * b.w;
            acc[1][0] += a.y * b.x; acc[1][1] += a.y * b.y;
            acc[1][2] += a.y * b.z; acc[1][3] += a.y * b.w;
            acc[2][0] += a.z * b.x; acc[2][1] += a.z * b.y;
            acc[2][2] += a.z * b.z; acc[2][3] += a.z * b.w;
            acc[3][0] += a.w * b.x; acc[3][1] += a.w * b.y;
            acc[3][2] += a.w * b.z; acc[3][3] += a.w * b.w;
        }
        __syncthreads();
    }

#pragma unroll
    for (int ii = 0; ii < 4; ii++) {
        int m = bm + (ty << 2) + ii;
        int orow;
        if (mode == 0) orow = m;
        else {
            int bb = m >> 7, l = m & 127;
            int ll = (mode == 1) ? l : (127 - l);
            orow = ll * B_ + bb;
        }
#pragma unroll
        for (int jj = 0; jj < 4; jj++) {
            int n = bn + (tx << 2) + jj;
            if (n < N) {
                float v = acc[ii][jj] + bias[n];
                if (act) v = v > 0.f ? v : expm1f(v);
                C[orow * N + n] = v;
            }
        }
    }
}

// ---------------------------------------------------------------------------
// Kernel 3: persistent MFMA BLSTM, fence-free agent-scope coherence.
// 64 blocks (32/dir), 4 waves = 4 gates, 16 units/block.
//  - W_hh fp16 A-frags in registers (64 VGPR), loaded once.
//  - h: single fp16 plane, [b][512], packed as u32 pairs; double-buffered.
//    All h global traffic via RELAXED agent atomics (sc1, MALL-coherent,
//    no wbl2/inv).  Writer ordering: __syncthreads() drains vmcnt(0).
//  - h staged once per block per step into XOR-swizzled LDS; B-frags via
//    conflict-free ds_read_b128.
//  - Arrival flags: one u32 per block, monotonic t+1; readers poll the 32
//    same-direction flags with relaxed loads.
// ---------------------------------------------------------------------------
__global__ __launch_bounds__(256) void lstm_mfma2(
    const float* __restrict__ gxf, const float* __restrict__ gxb,
    const _Float16* __restrict__ whh_h,      // [2][2048][512] fp16
    unsigned int* __restrict__ hbuf,         // [2 buf][2 dir][32][256] u32
    float* __restrict__ hcat, unsigned int* __restrict__ flags)  // [64]
{
    __shared__ unsigned int hlds[8192];      // 32 KB swizzled h
    __shared__ float gl[4 * 32 * 17];        // gate exchange

    int bx = blockIdx.x;
    int dir = bx >> 5;
    int U0 = (bx & 31) * 16;
    int tid = threadIdx.x;
    int g = tid >> 6;              // wave = gate (i,f,g,o)
    int l = tid & 63;
    int lr = l & 15, lk = l >> 4;  // frag row / k-chunk

    const float* gx = dir ? gxb : gxf;

    // A-fragments: rows g*512+U0+lr, k = ks*32 + lk*8 .. +7
    half8 afrag[16];
    {
        const _Float16* wrow = whh_h + (size_t)dir * (2048 * 512)
                             + (size_t)(g * 512 + U0 + lr) * 512 + lk * 8;
#pragma unroll
        for (int ks = 0; ks < 16; ks++)
            afrag[ks] = *(const half8*)(wrow + ks * 32);
    }

    int uu = tid & 15, ub = tid >> 4;   // update map: unit uu, batches ub/ub+16
    float c0 = 0.f, c1 = 0.f;
    const unsigned int* dflags = flags + dir * 32;

    for (int t = 0; t < L_; t++) {
        // ---- wait for peers' h_{t-1} (relaxed polls, no cache maintenance)
        if (t > 0) {
            unsigned tgt = (unsigned)t;
            int fi = tid & 31;
            while (__hip_atomic_load(&dflags[fi], __ATOMIC_RELAXED, AGENT_SC) < tgt)
                __builtin_amdgcn_s_sleep(1);
            __builtin_amdgcn_sched_barrier(0);
        }

        // ---- stage h_{t-1} (buf (t+1)&1) into swizzled LDS: 32 u32/thread
        {
            const unsigned int* hsrc = hbuf + ((((t + 1) & 1) * 2 + dir) * (32 * 256));
            unsigned int tmp[32];
#pragma unroll
            for (int p = 0; p < 32; p++)
                tmp[p] = __hip_atomic_load(&hsrc[tid + p * 256],
                                           __ATOMIC_RELAXED, AGENT_SC);
#pragma unroll
            for (int p = 0; p < 32; p++) {
                int w = tid + p * 256;
                int byte = (w << 2);
                int row = w >> 8;
                hlds[(byte ^ ((row & 7) << 4)) >> 2] = tmp[p];
            }
        }

        // ---- gx prefetch (normal cached loads; hidden under MFMA phase)
        float gxv0[4], gxv1[4];
        {
            const float* gxt = gx + (size_t)t * B_ * G4_;
#pragma unroll
            for (int gg = 0; gg < 4; gg++) {
                gxv0[gg] = gxt[ub * G4_ + gg * H_ + U0 + uu];
                gxv1[gg] = gxt[(ub + 16) * G4_ + gg * H_ + U0 + uu];
            }
        }
        __syncthreads();   // hlds ready

        // ---- MFMA: D[16 units][32 b] for this wave's gate
        f32x4 d0 = {0.f, 0.f, 0.f, 0.f};
        f32x4 d1 = {0.f, 0.f, 0.f, 0.f};
        const char* hb = (const char*)hlds;
        int base0 = lr * 1024 + lk * 16;
        int base1 = (16 + lr) * 1024 + lk * 16;
        int sw0 = (lr & 7) << 4;
        int sw1 = sw0;                  // ((16+lr)&7) == (lr&7)
#pragma unroll
        for (int ks = 0; ks < 16; ks++) {
            half8 b0 = *(const half8*)(hb + ((base0 + ks * 64) ^ sw0));
            half8 b1 = *(const half8*)(hb + ((base1 + ks * 64) ^ sw1));
            d0 = __builtin_amdgcn_mfma_f32_16x16x32_f16(afrag[ks], b0, d0, 0, 0, 0);
            d1 = __builtin_amdgcn_mfma_f32_16x16x32_f16(afrag[ks], b1, d1, 0, 0, 0);
        }
#pragma unroll
        for (int r = 0; r < 4; r++) {
            gl[(g * 32 + lr) * 17 + lk * 4 + r]      = d0[r];
            gl[(g * 32 + 16 + lr) * 17 + lk * 4 + r] = d1[r];
        }
        __syncthreads();

        // ---- cell update: (b=ub, j=U0+uu) and (b=ub+16, j)
        {
            float ga0[4], ga1[4];
#pragma unroll
            for (int gg = 0; gg < 4; gg++) {
                ga0[gg] = gl[(gg * 32 + ub) * 17 + uu] + gxv0[gg];
                ga1[gg] = gl[(gg * 32 + ub + 16) * 17 + uu] + gxv1[gg];
            }
            float i0 = 1.f / (1.f + expf(-ga0[0]));
            float f0_ = 1.f / (1.f + expf(-ga0[1]));
            float g0 = tanhf(ga0[2]);
            float o0 = 1.f / (1.f + expf(-ga0[3]));
            c0 = f0_ * c0 + i0 * g0;
            float h0 = o0 * tanhf(c0);

            float i1 = 1.f / (1.f + expf(-ga1[0]));
            float f1_ = 1.f / (1.f + expf(-ga1[1]));
            float g1 = tanhf(ga1[2]);
            float o1 = 1.f / (1.f + expf(-ga1[3]));
            c1 = f1_ * c1 + i1 * g1;
            float h1 = o1 * tanhf(c1);

            int j = U0 + uu;
            int ll = dir ? (L_ - 1 - t) : t;
            hcat[((size_t)ub * L_ + ll) * (2 * H_) + dir * H_ + j]        = h0;
            hcat[((size_t)(ub + 16) * L_ + ll) * (2 * H_) + dir * H_ + j] = h1;

            // pack (j, j^1) fp16 pairs across even/odd lanes, sc1-store
            float h0n = __shfl_xor(h0, 1);
            float h1n = __shfl_xor(h1, 1);
            if ((uu & 1) == 0) {
                union { _Float16 h[2]; unsigned u; } p0, p1;
                p0.h[0] = (_Float16)h0; p0.h[1] = (_Float16)h0n;
                p1.h[0] = (_Float16)h1; p1.h[1] = (_Float16)h1n;
                unsigned int* hdst = hbuf + (((t & 1) * 2 + dir) * (32 * 256));
                int wj = (U0 + uu) >> 1;
                __hip_atomic_store(&hdst[ub * 256 + wj], p0.u,
                                   __ATOMIC_RELAXED, AGENT_SC);
                __hip_atomic_store(&hdst[(ub + 16) * 256 + wj], p1.u,
                                   __ATOMIC_RELAXED, AGENT_SC);
            }
        }

        // ---- arrive: syncthreads drains vmcnt(0) -> all h stores at MALL
        __syncthreads();
        if (tid == 0)
            __hip_atomic_store((unsigned int*)&flags[bx], (unsigned)(t + 1),
                               __ATOMIC_RELAXED, AGENT_SC);
    }
}

// ---------------------------------------------------------------------------
// Launch
// ---------------------------------------------------------------------------
extern "C" void kernel_launch(void* const* d_in, const int* in_sizes, int n_in,
                              void* d_out, int out_size, void* d_ws, size_t ws_size,
                              hipStream_t stream)
{
    const int*   word_ids = (const int*)d_in[0];
    const int*   char_ids = (const int*)d_in[1];
    const float* char_emb = (const float*)d_in[3];
    const float* word_emb = (const float*)d_in[4];
    const float* conv_w   = (const float*)d_in[5];
    const float* conv_b   = (const float*)d_in[6];
    const float* w_ih_f   = (const float*)d_in[7];
    const float* w_hh_f   = (const float*)d_in[8];
    const float* b_f      = (const float*)d_in[9];
    const float* w_ih_b   = (const float*)d_in[10];
    const float* w_hh_b   = (const float*)d_in[11];
    const float* b_b      = (const float*)d_in[12];
    const float* w1       = (const float*)d_in[13];
    const float* b1       = (const float*)d_in[14];
    const float* w2       = (const float*)d_in[15];
    const float* b2       = (const float*)d_in[16];
    float* out = (float*)d_out;
    float* ws  = (float*)d_ws;

    // workspace layout (float offsets)
    float* x    = ws + 0;            // [4096][384]
    float* gxf  = ws + 1572864;      // [128][32][2048]
    float* gxb  = ws + 9961472;      // [128][32][2048]
    float* hcat = ws + 18350080;     // [4096][1024]
    _Float16* whhh = (_Float16*)(ws + 22544384);          // 2x2048x512 fp16
    unsigned int* hbuf = (unsigned int*)(ws + 23592960);  // 2x2x32x256 u32
    float* cwT  = ws + 23658496;     // [64][3][128]
    unsigned int* flags = (unsigned int*)(ws + 23683072); // [64]
    float* z    = ws + 0;            // [4096][512] reuses x (dead by then)

    hipMemsetAsync(hbuf, 0, 2 * 2 * 32 * 256 * sizeof(unsigned int), stream);
    hipMemsetAsync(flags, 0, 64 * sizeof(unsigned int), stream);

    conv_transpose_k<<<96, 256, 0, stream>>>(conv_w, cwT);
    whh_to_f16<<<2048, 256, 0, stream>>>(w_hh_f, w_hh_b, whhh);
    embed_cnn<<<4096, 64, 0, stream>>>(word_ids, char_ids, char_emb, word_emb,
                                       cwT, conv_b, x);

    dim3 g1(64, 32);
    gemm_bias_act<<<g1, 256, 0, stream>>>(x, w_ih_f, b_f, gxf, 4096, G4_, E_, 1, 0);
    gemm_bias_act<<<g1, 256, 0, stream>>>(x, w_ih_b, b_b, gxb, 4096, G4_, E_, 2, 0);

    {
        const float* a0 = gxf; const float* a1 = gxb;
        const _Float16* a2 = whhh;
        unsigned int* a3 = hbuf;
        float* a4 = hcat;
        unsigned int* a5 = flags;
        void* args[] = { &a0, &a1, &a2, &a3, &a4, &a5 };
        hipLaunchCooperativeKernel((void*)lstm_mfma2, dim3(LSTM_BLOCKS), dim3(256),
                                   args, 0, stream);
    }

    dim3 g2(64, 8);
    gemm_bias_act<<<g2, 256, 0, stream>>>(hcat, w1, b1, z, 4096, O1_, 2 * H_, 0, 1);
    dim3 g3(64, 1);
    gemm_bias_act<<<g3, 256, 0, stream>>>(z, w2, b2, out, 4096, NC_, O1_, 0, 0);
}

// Round 7
// 715.600 us; speedup vs baseline: 8.3591x; 1.2729x over previous
//
#include <hip/hip_runtime.h>
#include <math.h>

// Problem constants
#define B_   32
#define L_   128
#define W_   16
#define CE_  64     // char embed
#define NF_  128    // num filters
#define WE_  256    // word embed
#define E_   384    // NF_ + WE_
#define H_   512
#define G4_  2048   // 4*H
#define O1_  512
#define NC_  17
#define LSTM_BLOCKS 64          // 32 per direction
#define AGENT_SC __HIP_MEMORY_SCOPE_AGENT

typedef __attribute__((ext_vector_type(4))) float f32x4;
typedef _Float16 half8 __attribute__((ext_vector_type(8)));
typedef _Float16 half4 __attribute__((ext_vector_type(4)));

__device__ inline half8 cvt8(float4 a, float4 b) {
    half8 r;
    r[0] = (_Float16)a.x; r[1] = (_Float16)a.y;
    r[2] = (_Float16)a.z; r[3] = (_Float16)a.w;
    r[4] = (_Float16)b.x; r[5] = (_Float16)b.y;
    r[6] = (_Float16)b.z; r[7] = (_Float16)b.w;
    return r;
}

// ---------------------------------------------------------------------------
// Kernel 0: transpose conv weights [F][C][K] -> [C][K][F]
// ---------------------------------------------------------------------------
__global__ __launch_bounds__(256) void conv_transpose_k(
    const float* __restrict__ cw, float* __restrict__ cwT)
{
    int i = blockIdx.x * 256 + threadIdx.x;   // 24576 exact
    int f = i / 192;
    int rem = i - f * 192;
    int c = rem / 3;
    int k = rem - c * 3;
    cwT[(c * 3 + k) * NF_ + f] = cw[i];
}

// ---------------------------------------------------------------------------
// Kernel 1: char embed gather + conv1d(k=3,pad=1) + relu + maxpool + word
// embed concat -> x_h [B*L, 384] fp16
// ---------------------------------------------------------------------------
__global__ __launch_bounds__(64) void embed_cnn(
    const int* __restrict__ word_ids, const int* __restrict__ char_ids,
    const float* __restrict__ char_emb, const float* __restrict__ word_emb,
    const float* __restrict__ cwT, const float* __restrict__ conv_b,
    _Float16* __restrict__ x_h)
{
    __shared__ float ce[CE_][20];
    __shared__ int ids[W_];
    int bl = blockIdx.x;
    int tid = threadIdx.x;

    if (tid < W_) ids[tid] = char_ids[bl * W_ + tid];
    ce[tid][0] = 0.f;
    ce[tid][17] = 0.f;
    __syncthreads();

    for (int i = tid; i < W_ * CE_; i += 64) {
        int w = i >> 6, c = i & 63;
        ce[c][w + 1] = char_emb[ids[w] * CE_ + c];
    }
    __syncthreads();

    int f0 = tid, f1 = tid + 64;
    float acc0[W_], acc1[W_];
#pragma unroll
    for (int w = 0; w < W_; w++) { acc0[w] = 0.f; acc1[w] = 0.f; }

    for (int c = 0; c < CE_; c++) {
        float win[18];
        float4 v0 = *(const float4*)&ce[c][0];
        float4 v1 = *(const float4*)&ce[c][4];
        float4 v2 = *(const float4*)&ce[c][8];
        float4 v3 = *(const float4*)&ce[c][12];
        win[0]=v0.x; win[1]=v0.y; win[2]=v0.z; win[3]=v0.w;
        win[4]=v1.x; win[5]=v1.y; win[6]=v1.z; win[7]=v1.w;
        win[8]=v2.x; win[9]=v2.y; win[10]=v2.z; win[11]=v2.w;
        win[12]=v3.x; win[13]=v3.y; win[14]=v3.z; win[15]=v3.w;
        win[16] = ce[c][16];
        win[17] = ce[c][17];
        const float* wp = cwT + c * 3 * NF_;
        float k00 = wp[f0], k01 = wp[NF_ + f0], k02 = wp[2 * NF_ + f0];
        float k10 = wp[f1], k11 = wp[NF_ + f1], k12 = wp[2 * NF_ + f1];
#pragma unroll
        for (int w = 0; w < W_; w++) {
            acc0[w] += win[w] * k00 + win[w + 1] * k01 + win[w + 2] * k02;
            acc1[w] += win[w] * k10 + win[w + 1] * k11 + win[w + 2] * k12;
        }
    }
    float m0 = acc0[0], m1 = acc1[0];
#pragma unroll
    for (int w = 1; w < W_; w++) { m0 = fmaxf(m0, acc0[w]); m1 = fmaxf(m1, acc1[w]); }
    m0 = fmaxf(0.f, m0 + conv_b[f0]);
    m1 = fmaxf(0.f, m1 + conv_b[f1]);
    x_h[bl * E_ + f0] = (_Float16)m0;
    x_h[bl * E_ + f1] = (_Float16)m1;

    int wid = word_ids[bl];
    float4 wv = *(const float4*)&word_emb[wid * WE_ + tid * 4];
    half4 h;
    h[0] = (_Float16)wv.x; h[1] = (_Float16)wv.y;
    h[2] = (_Float16)wv.z; h[3] = (_Float16)wv.w;
    *(half4*)&x_h[bl * E_ + NF_ + tid * 4] = h;
}

// ---------------------------------------------------------------------------
// Kernel 2: fp16 MFMA GEMM  C = A[M,K]h @ W[N,K]f32^T + bias.
// 64x64 tile, 256 threads = 4 waves (wave = 16-row M strip x 64 N).
// W converted f32->f16 during LDS staging. XOR-swizzled LDS, 16x16x32 MFMA.
// mode 0: C[m][n]; 1/2: C[(l or 127-l)*B + b][n]. act: ELU.
// fp16out: store _Float16 (for gx), else float.
// ---------------------------------------------------------------------------
__global__ __launch_bounds__(256) void gemm_f16(
    const _Float16* __restrict__ A, const float* __restrict__ Wt,
    const float* __restrict__ bias, void* __restrict__ C,
    int N, int K, int mode, int act, int fp16out)
{
    __shared__ _Float16 As[64 * 32];
    __shared__ _Float16 Bs[64 * 32];
    int tid = threadIdx.x;
    int bm = blockIdx.x * 64;
    int bn = blockIdx.y * 64;
    int l = tid & 63;
    int mt = tid >> 6;             // wave id = m-tile
    int lr = l & 15, lk = l >> 4;

    int srow = tid >> 2, skq = (tid & 3) << 3;   // staging: row 0..63, k 0..31
    int sbyteA = ((srow * 64 + skq * 2) ^ ((srow & 7) << 4));

    f32x4 d[4] = {{0.f,0.f,0.f,0.f},{0.f,0.f,0.f,0.f},
                  {0.f,0.f,0.f,0.f},{0.f,0.f,0.f,0.f}};

    for (int kt = 0; kt < K; kt += 32) {
        // stage A (fp16 load) and W (f32 load + cvt)
        half8 av = *(const half8*)&A[(size_t)(bm + srow) * K + kt + skq];
        const float* wp = &Wt[(size_t)(bn + srow) * K + kt + skq];
        float4 w0 = *(const float4*)wp;
        float4 w1 = *(const float4*)(wp + 4);
        *(half8*)((char*)As + sbyteA) = av;
        *(half8*)((char*)Bs + sbyteA) = cvt8(w0, w1);
        __syncthreads();

        // fragments + MFMA
        int arow = mt * 16 + lr;
        half8 af = *(const half8*)((char*)As +
                     ((arow * 64 + lk * 16) ^ ((arow & 7) << 4)));
#pragma unroll
        for (int nt = 0; nt < 4; nt++) {
            int brow = nt * 16 + lr;
            half8 bf = *(const half8*)((char*)Bs +
                         ((brow * 64 + lk * 16) ^ ((brow & 7) << 4)));
            d[nt] = __builtin_amdgcn_mfma_f32_16x16x32_f16(af, bf, d[nt], 0, 0, 0);
        }
        __syncthreads();
    }

    // epilogue: m = bm + mt*16 + lk*4 + r, n = bn + nt*16 + lr
#pragma unroll
    for (int nt = 0; nt < 4; nt++) {
        int n = bn + nt * 16 + lr;
        float bv = bias[n];
#pragma unroll
        for (int r = 0; r < 4; r++) {
            int m = bm + mt * 16 + lk * 4 + r;
            int orow;
            if (mode == 0) orow = m;
            else {
                int bb = m >> 7, ll = m & 127;
                if (mode == 2) ll = 127 - ll;
                orow = ll * B_ + bb;
            }
            float v = d[nt][r] + bv;
            if (act) v = v > 0.f ? v : expm1f(v);
            if (fp16out) ((_Float16*)C)[(size_t)orow * N + n] = (_Float16)v;
            else         ((float*)C)[(size_t)orow * N + n] = v;
        }
    }
}

// ---------------------------------------------------------------------------
// Kernel 2b: small fp32 GEMM for the head2 (N=17)
// ---------------------------------------------------------------------------
__global__ __launch_bounds__(256) void gemm_bias_act(
    const float* __restrict__ A, const float* __restrict__ Wt,
    const float* __restrict__ bias, float* __restrict__ C,
    int M, int N, int K)
{
    __shared__ float As[16][68];
    __shared__ float Bs[16][68];
    int tid = threadIdx.x;
    int bm = blockIdx.x * 64;
    int bn = blockIdx.y * 64;
    int tx = tid & 15, ty = tid >> 4;
    int r = tid >> 2, kq = (tid & 3) << 2;
    float acc[4][4] = {};

    for (int kt = 0; kt < K; kt += 16) {
        float4 av = *(const float4*)&A[(bm + r) * K + kt + kq];
        As[kq + 0][r] = av.x; As[kq + 1][r] = av.y;
        As[kq + 2][r] = av.z; As[kq + 3][r] = av.w;
        int n = bn + r;
        float4 wv = make_float4(0.f, 0.f, 0.f, 0.f);
        if (n < N) wv = *(const float4*)&Wt[n * K + kt + kq];
        Bs[kq + 0][r] = wv.x; Bs[kq + 1][r] = wv.y;
        Bs[kq + 2][r] = wv.z; Bs[kq + 3][r] = wv.w;
        __syncthreads();
#pragma unroll
        for (int k = 0; k < 16; k++) {
            float4 a = *(const float4*)&As[k][ty << 2];
            float4 b = *(const float4*)&Bs[k][tx << 2];
            acc[0][0] += a.x * b.x; acc[0][1] += a.x * b.y;
            acc[0][2] += a.x * b.z; acc[0][3] += a.x * b.w;
            acc[1][0] += a.y * b.x; acc[1][1] += a.y * b.y;
            acc[1][2] += a.y * b.z; acc[1][3] += a.y * b.w;
            acc[2][0] += a.z * b.x; acc[2][1] += a.z * b.y;
            acc[2][2] += a.z * b.z; acc[2][3] += a.z * b.w;
            acc[3][0] += a.w * b.x; acc[3][1] += a.w * b.y;
            acc[3][2] += a.w * b.z; acc[3][3] += a.w * b.w;
        }
        __syncthreads();
    }

#pragma unroll
    for (int ii = 0; ii < 4; ii++) {
        int m = bm + (ty << 2) + ii;
#pragma unroll
        for (int jj = 0; jj < 4; jj++) {
            int n = bn + (tx << 2) + jj;
            if (n < N) C[m * N + n] = acc[ii][jj] + bias[n];
        }
    }
}

// ---------------------------------------------------------------------------
// Kernel 3: persistent MFMA BLSTM, fence-free agent-scope coherence.
// (structure validated round 5; W_hh f32->f16 cvt at frag load; hcat fp16)
// ---------------------------------------------------------------------------
__global__ __launch_bounds__(256) void lstm_mfma2(
    const float* __restrict__ gxf, const float* __restrict__ gxb,
    const float* __restrict__ whh_f, const float* __restrict__ whh_b,
    unsigned int* __restrict__ hbuf,         // [2 buf][2 dir][32][256] u32
    _Float16* __restrict__ hcat_h,           // [4096][1024] fp16
    unsigned int* __restrict__ flags)        // [64]
{
    __shared__ unsigned int hlds[8192];      // 32 KB swizzled h
    __shared__ float gl[4 * 32 * 17];        // gate exchange

    int bx = blockIdx.x;
    int dir = bx >> 5;
    int U0 = (bx & 31) * 16;
    int tid = threadIdx.x;
    int g = tid >> 6;              // wave = gate (i,f,g,o)
    int l = tid & 63;
    int lr = l & 15, lk = l >> 4;  // frag row / k-chunk

    const float* gx = dir ? gxb : gxf;

    // A-fragments: rows g*512+U0+lr, k = ks*32 + lk*8 .. +7 (f32 -> f16)
    half8 afrag[16];
    {
        const float* wrow = (dir ? whh_b : whh_f)
                          + (size_t)(g * 512 + U0 + lr) * 512 + lk * 8;
#pragma unroll
        for (int ks = 0; ks < 16; ks++) {
            float4 a = *(const float4*)(wrow + ks * 32);
            float4 b = *(const float4*)(wrow + ks * 32 + 4);
            afrag[ks] = cvt8(a, b);
        }
    }

    int uu = tid & 15, ub = tid >> 4;   // update map: unit uu, batches ub/ub+16
    float c0 = 0.f, c1 = 0.f;
    const unsigned int* dflags = flags + dir * 32;

    for (int t = 0; t < L_; t++) {
        // ---- wait for peers' h_{t-1} (relaxed polls, no cache maintenance)
        if (t > 0) {
            unsigned tgt = (unsigned)t;
            int fi = tid & 31;
            while (__hip_atomic_load(&dflags[fi], __ATOMIC_RELAXED, AGENT_SC) < tgt)
                __builtin_amdgcn_s_sleep(1);
            __builtin_amdgcn_sched_barrier(0);
        }

        // ---- stage h_{t-1} (buf (t+1)&1) into swizzled LDS: 32 u32/thread
        {
            const unsigned int* hsrc = hbuf + ((((t + 1) & 1) * 2 + dir) * (32 * 256));
            unsigned int tmp[32];
#pragma unroll
            for (int p = 0; p < 32; p++)
                tmp[p] = __hip_atomic_load(&hsrc[tid + p * 256],
                                           __ATOMIC_RELAXED, AGENT_SC);
#pragma unroll
            for (int p = 0; p < 32; p++) {
                int w = tid + p * 256;
                int byte = (w << 2);
                int row = w >> 8;
                hlds[(byte ^ ((row & 7) << 4)) >> 2] = tmp[p];
            }
        }

        // ---- gx prefetch (normal cached loads; hidden under MFMA phase)
        float gxv0[4], gxv1[4];
        {
            const float* gxt = gx + (size_t)t * B_ * G4_;
#pragma unroll
            for (int gg = 0; gg < 4; gg++) {
                gxv0[gg] = gxt[ub * G4_ + gg * H_ + U0 + uu];
                gxv1[gg] = gxt[(ub + 16) * G4_ + gg * H_ + U0 + uu];
            }
        }
        __syncthreads();   // hlds ready

        // ---- MFMA: D[16 units][32 b] for this wave's gate
        f32x4 d0 = {0.f, 0.f, 0.f, 0.f};
        f32x4 d1 = {0.f, 0.f, 0.f, 0.f};
        const char* hb = (const char*)hlds;
        int base0 = lr * 1024 + lk * 16;
        int base1 = (16 + lr) * 1024 + lk * 16;
        int sw0 = (lr & 7) << 4;
#pragma unroll
        for (int ks = 0; ks < 16; ks++) {
            half8 b0 = *(const half8*)(hb + ((base0 + ks * 64) ^ sw0));
            half8 b1 = *(const half8*)(hb + ((base1 + ks * 64) ^ sw0));
            d0 = __builtin_amdgcn_mfma_f32_16x16x32_f16(afrag[ks], b0, d0, 0, 0, 0);
            d1 = __builtin_amdgcn_mfma_f32_16x16x32_f16(afrag[ks], b1, d1, 0, 0, 0);
        }
#pragma unroll
        for (int r = 0; r < 4; r++) {
            gl[(g * 32 + lr) * 17 + lk * 4 + r]      = d0[r];
            gl[(g * 32 + 16 + lr) * 17 + lk * 4 + r] = d1[r];
        }
        __syncthreads();

        // ---- cell update: (b=ub, j=U0+uu) and (b=ub+16, j)
        {
            float ga0[4], ga1[4];
#pragma unroll
            for (int gg = 0; gg < 4; gg++) {
                ga0[gg] = gl[(gg * 32 + ub) * 17 + uu] + gxv0[gg];
                ga1[gg] = gl[(gg * 32 + ub + 16) * 17 + uu] + gxv1[gg];
            }
            float i0 = 1.f / (1.f + expf(-ga0[0]));
            float f0_ = 1.f / (1.f + expf(-ga0[1]));
            float g0 = tanhf(ga0[2]);
            float o0 = 1.f / (1.f + expf(-ga0[3]));
            c0 = f0_ * c0 + i0 * g0;
            float h0 = o0 * tanhf(c0);

            float i1 = 1.f / (1.f + expf(-ga1[0]));
            float f1_ = 1.f / (1.f + expf(-ga1[1]));
            float g1 = tanhf(ga1[2]);
            float o1 = 1.f / (1.f + expf(-ga1[3]));
            c1 = f1_ * c1 + i1 * g1;
            float h1 = o1 * tanhf(c1);

            int j = U0 + uu;
            int ll = dir ? (L_ - 1 - t) : t;
            hcat_h[((size_t)ub * L_ + ll) * (2 * H_) + dir * H_ + j]        = (_Float16)h0;
            hcat_h[((size_t)(ub + 16) * L_ + ll) * (2 * H_) + dir * H_ + j] = (_Float16)h1;

            // pack (j, j^1) fp16 pairs across even/odd lanes, sc1-store
            float h0n = __shfl_xor(h0, 1);
            float h1n = __shfl_xor(h1, 1);
            if ((uu & 1) == 0) {
                union { _Float16 h[2]; unsigned u; } p0, p1;
                p0.h[0] = (_Float16)h0; p0.h[1] = (_Float16)h0n;
                p1.h[0] = (_Float16)h1; p1.h[1] = (_Float16)h1n;
                unsigned int* hdst = hbuf + (((t & 1) * 2 + dir) * (32 * 256));
                int wj = (U0 + uu) >> 1;
                __hip_atomic_store(&hdst[ub * 256 + wj], p0.u,
                                   __ATOMIC_RELAXED, AGENT_SC);
                __hip_atomic_store(&hdst[(ub + 16) * 256 + wj], p1.u,
                                   __ATOMIC_RELAXED, AGENT_SC);
            }
        }

        // ---- arrive: syncthreads drains vmcnt(0) -> all h stores at MALL
        __syncthreads();
        if (tid == 0)
            __hip_atomic_store((unsigned int*)&flags[bx], (unsigned)(t + 1),
                               __ATOMIC_RELAXED, AGENT_SC);
    }
}

// ---------------------------------------------------------------------------
// Launch
// ---------------------------------------------------------------------------
extern "C" void kernel_launch(void* const* d_in, const int* in_sizes, int n_in,
                              void* d_out, int out_size, void* d_ws, size_t ws_size,
                              hipStream_t stream)
{
    const int*   word_ids = (const int*)d_in[0];
    const int*   char_ids = (const int*)d_in[1];
    const float* char_emb = (const float*)d_in[3];
    const float* word_emb = (const float*)d_in[4];
    const float* conv_w   = (const float*)d_in[5];
    const float* conv_b   = (const float*)d_in[6];
    const float* w_ih_f   = (const float*)d_in[7];
    const float* w_hh_f   = (const float*)d_in[8];
    const float* b_f      = (const float*)d_in[9];
    const float* w_ih_b   = (const float*)d_in[10];
    const float* w_hh_b   = (const float*)d_in[11];
    const float* b_b      = (const float*)d_in[12];
    const float* w1       = (const float*)d_in[13];
    const float* b1       = (const float*)d_in[14];
    const float* w2       = (const float*)d_in[15];
    const float* b2       = (const float*)d_in[16];
    float* out = (float*)d_out;
    float* ws  = (float*)d_ws;

    // workspace layout (f32 offsets), total ~21.9M f32 = 87.4 MB
    _Float16* x_h   = (_Float16*)(ws + 0);            // [4096][384] fp16
    float* gxf  = ws + 786432;       // [128][32][2048] f32
    float* gxb  = ws + 9175040;      // [128][32][2048] f32
    _Float16* hcat_h = (_Float16*)(ws + 17563648);    // [4096][1024] fp16
    float* z    = ws + 19660800;     // [4096][512] f32
    unsigned int* hbuf = (unsigned int*)(ws + 21757952);  // [2][2][32][256] u32
    float* cwT  = ws + 21823488;     // [64][3][128]
    unsigned int* flags = (unsigned int*)(ws + 21848064); // [64]

    hipMemsetAsync(hbuf, 0, 2 * 2 * 32 * 256 * sizeof(unsigned int), stream);
    hipMemsetAsync(flags, 0, 64 * sizeof(unsigned int), stream);

    conv_transpose_k<<<96, 256, 0, stream>>>(conv_w, cwT);
    embed_cnn<<<4096, 64, 0, stream>>>(word_ids, char_ids, char_emb, word_emb,
                                       cwT, conv_b, x_h);

    // input projections -> gx (time-major f32), fp16 MFMA
    dim3 g1(64, 32);
    gemm_f16<<<g1, 256, 0, stream>>>(x_h, w_ih_f, b_f, gxf, G4_, E_, 1, 0, 0);
    gemm_f16<<<g1, 256, 0, stream>>>(x_h, w_ih_b, b_b, gxb, G4_, E_, 2, 0, 0);

    {
        const float* a0 = gxf; const float* a1 = gxb;
        const float* a2 = w_hh_f; const float* a3 = w_hh_b;
        unsigned int* a4 = hbuf;
        _Float16* a5 = hcat_h;
        unsigned int* a6 = flags;
        void* args[] = { &a0, &a1, &a2, &a3, &a4, &a5, &a6 };
        hipLaunchCooperativeKernel((void*)lstm_mfma2, dim3(LSTM_BLOCKS), dim3(256),
                                   args, 0, stream);
    }

    // head1: z = ELU(hcat @ w1^T + b1), fp16 MFMA, fp32 out
    dim3 g2(64, 8);
    gemm_f16<<<g2, 256, 0, stream>>>(hcat_h, w1, b1, z, O1_, 2 * H_, 0, 1, 0);
    // head2: out = z @ w2^T + b2 (small fp32)
    dim3 g3(64, 1);
    gemm_bias_act<<<g3, 256, 0, stream>>>(z, w2, b2, out, 4096, NC_, O1_);
}